// Round 7
// baseline (386.052 us; speedup 1.0000x reference)
//
#include <hip/hip_runtime.h>
#include <hip/hip_bf16.h>

#define TOKENS 16384
#define DMODEL 2048
#define NEXP   64
#define NCH    (DMODEL / 4)     // 512 chunks of 4 k-values
#define NWIN   32               // windows of 16 chunks
#define TPB    32               // tokens per block
#define TPW    8                // tokens per wave

// out layout (floats): probs[T*2] | indices[T*2] | tokens_per_expert[64] | aux[1]
#define OFF_IDX  (TOKENS * 2)
#define OFF_HIST (TOKENS * 4)
#define OFF_AUX  (TOKENS * 4 + NEXP)

#define W4_FLOATS (DMODEL * NEXP)   // 131072 floats = 512 KB

// w4[k4][e][j] = gw[e][4*k4+j] : one coalesced dwordx4 per lane per chunk
__global__ __launch_bounds__(256) void transpose_w(const float* __restrict__ gw,
                                                   float* __restrict__ w4)
{
    int idx = blockIdx.x * 256 + threadIdx.x;   // 0..32767
    int e  = idx & 63;
    int k4 = idx >> 6;
    float4 v = *(const float4*)(gw + (size_t)e * DMODEL + k4 * 4);
    *(float4*)(w4 + (size_t)idx * 4) = v;       // contiguous writes
}

struct Bank {
    float4 r0, r1, r2, r3, r4, r5, r6, r7;  // X broadcasts, tokens 0..7
    float4 w;                               // W chunk (lane = expert)
};

template<bool USE_W4>
__global__ __launch_bounds__(256, 2) void router_kernel(
    const float* __restrict__ x,      // [T, D]
    const float* __restrict__ gw,     // [E, D]
    const float* __restrict__ w4,     // [D/4, E, 4] transposed W (if USE_W4)
    float* __restrict__ out,
    float* __restrict__ probsum_g,
    float* __restrict__ hist_g)
{
    __shared__ float psum_s[4][NEXP];
    __shared__ int   hist_s[NEXP];

    const int tid  = threadIdx.x;
    const int wave = tid >> 6;
    const int lane = tid & 63;
    const int tko  = __builtin_amdgcn_readfirstlane((int)(blockIdx.x * TPB) + wave * TPW);

    if (tid < NEXP) hist_s[tid] = 0;

    // opaque divergent zero: forces vector (saddr+voffset) loads for X broadcasts
    int lz;
    asm("v_mov_b32 %0, 0" : "=v"(lz));

    // uniform per-token base pointers (SGPR pairs)
    const float* xp0 = x + (size_t)(tko + 0) * DMODEL;
    const float* xp1 = x + (size_t)(tko + 1) * DMODEL;
    const float* xp2 = x + (size_t)(tko + 2) * DMODEL;
    const float* xp3 = x + (size_t)(tko + 3) * DMODEL;
    const float* xp4 = x + (size_t)(tko + 4) * DMODEL;
    const float* xp5 = x + (size_t)(tko + 5) * DMODEL;
    const float* xp6 = x + (size_t)(tko + 6) * DMODEL;
    const float* xp7 = x + (size_t)(tko + 7) * DMODEL;
    const float* gwd = gw + (size_t)lane * DMODEL;   // fallback W gather base

    float acc[8];
#pragma unroll
    for (int t = 0; t < 8; ++t) acc[t] = 0.f;

    auto LOADB = [&](Bank& B, int C) __attribute__((always_inline)) {
        B.r0 = *(const float4*)(xp0 + lz + (size_t)C * 4);
        B.r1 = *(const float4*)(xp1 + lz + (size_t)C * 4);
        B.r2 = *(const float4*)(xp2 + lz + (size_t)C * 4);
        B.r3 = *(const float4*)(xp3 + lz + (size_t)C * 4);
        B.r4 = *(const float4*)(xp4 + lz + (size_t)C * 4);
        B.r5 = *(const float4*)(xp5 + lz + (size_t)C * 4);
        B.r6 = *(const float4*)(xp6 + lz + (size_t)C * 4);
        B.r7 = *(const float4*)(xp7 + lz + (size_t)C * 4);
        B.w  = USE_W4 ? *(const float4*)(w4 + (size_t)C * (NEXP * 4) + (lane << 2))
                      : *(const float4*)(gwd + (size_t)C * 4);
    };

    auto FMAB = [&](Bank& B) __attribute__((always_inline)) {
        acc[0]=fmaf(B.r0.x,B.w.x,acc[0]); acc[0]=fmaf(B.r0.y,B.w.y,acc[0]);
        acc[0]=fmaf(B.r0.z,B.w.z,acc[0]); acc[0]=fmaf(B.r0.w,B.w.w,acc[0]);
        acc[1]=fmaf(B.r1.x,B.w.x,acc[1]); acc[1]=fmaf(B.r1.y,B.w.y,acc[1]);
        acc[1]=fmaf(B.r1.z,B.w.z,acc[1]); acc[1]=fmaf(B.r1.w,B.w.w,acc[1]);
        acc[2]=fmaf(B.r2.x,B.w.x,acc[2]); acc[2]=fmaf(B.r2.y,B.w.y,acc[2]);
        acc[2]=fmaf(B.r2.z,B.w.z,acc[2]); acc[2]=fmaf(B.r2.w,B.w.w,acc[2]);
        acc[3]=fmaf(B.r3.x,B.w.x,acc[3]); acc[3]=fmaf(B.r3.y,B.w.y,acc[3]);
        acc[3]=fmaf(B.r3.z,B.w.z,acc[3]); acc[3]=fmaf(B.r3.w,B.w.w,acc[3]);
        acc[4]=fmaf(B.r4.x,B.w.x,acc[4]); acc[4]=fmaf(B.r4.y,B.w.y,acc[4]);
        acc[4]=fmaf(B.r4.z,B.w.z,acc[4]); acc[4]=fmaf(B.r4.w,B.w.w,acc[4]);
        acc[5]=fmaf(B.r5.x,B.w.x,acc[5]); acc[5]=fmaf(B.r5.y,B.w.y,acc[5]);
        acc[5]=fmaf(B.r5.z,B.w.z,acc[5]); acc[5]=fmaf(B.r5.w,B.w.w,acc[5]);
        acc[6]=fmaf(B.r6.x,B.w.x,acc[6]); acc[6]=fmaf(B.r6.y,B.w.y,acc[6]);
        acc[6]=fmaf(B.r6.z,B.w.z,acc[6]); acc[6]=fmaf(B.r6.w,B.w.w,acc[6]);
        acc[7]=fmaf(B.r7.x,B.w.x,acc[7]); acc[7]=fmaf(B.r7.y,B.w.y,acc[7]);
        acc[7]=fmaf(B.r7.z,B.w.z,acc[7]); acc[7]=fmaf(B.r7.w,B.w.w,acc[7]);
    };

    Bank A, B, C, D;

    // prefetch touch for window w: 8 rows x 4 lines of its 256B k-slice;
    // sink is DELAYED a full window so the wait never lands on an in-flight miss
    float pfa = x[(size_t)(tko + (lane >> 3)) * DMODEL + 0 * 64 + ((lane & 3) << 4)];
    float pfb = x[(size_t)(tko + (lane >> 3)) * DMODEL + 1 * 64 + ((lane & 3) << 4)];

    LOADB(A, 0); LOADB(B, 1); LOADB(C, 2); LOADB(D, 3);

    for (int w = 0; w < NWIN - 1; ++w) {
        const int c0 = w * 16;
        float pfn = 0.f;
        if (w + 2 < NWIN)
            pfn = x[(size_t)(tko + (lane >> 3)) * DMODEL + (w + 2) * 64 + ((lane & 3) << 4)];

        FMAB(A); LOADB(A, c0 + 4);   FMAB(B); LOADB(B, c0 + 5);
        FMAB(C); LOADB(C, c0 + 6);   FMAB(D); LOADB(D, c0 + 7);
        FMAB(A); LOADB(A, c0 + 8);   FMAB(B); LOADB(B, c0 + 9);
        FMAB(C); LOADB(C, c0 + 10);  FMAB(D); LOADB(D, c0 + 11);
        FMAB(A); LOADB(A, c0 + 12);  FMAB(B); LOADB(B, c0 + 13);
        FMAB(C); LOADB(C, c0 + 14);  FMAB(D); LOADB(D, c0 + 15);
        FMAB(A); LOADB(A, c0 + 16);  FMAB(B); LOADB(B, c0 + 17);
        FMAB(C); LOADB(C, c0 + 18);  FMAB(D); LOADB(D, c0 + 19);

        asm volatile("" :: "v"(pfa));   // pf(w): issued 2 windows ago -> no stall
        pfa = pfb; pfb = pfn;
    }
    {   // peeled final window: chunks 496..511, no OOB reloads
        const int c0 = (NWIN - 1) * 16;
        FMAB(A); LOADB(A, c0 + 4);   FMAB(B); LOADB(B, c0 + 5);
        FMAB(C); LOADB(C, c0 + 6);   FMAB(D); LOADB(D, c0 + 7);
        FMAB(A); LOADB(A, c0 + 8);   FMAB(B); LOADB(B, c0 + 9);
        FMAB(C); LOADB(C, c0 + 10);  FMAB(D); LOADB(D, c0 + 11);
        FMAB(A); LOADB(A, c0 + 12);  FMAB(B); LOADB(B, c0 + 13);
        FMAB(C); LOADB(C, c0 + 14);  FMAB(D); LOADB(D, c0 + 15);
        FMAB(A); FMAB(B); FMAB(C); FMAB(D);
        asm volatile("" :: "v"(pfa));
        asm volatile("" :: "v"(pfb));
    }

    __syncthreads();   // hist_s init visible to all waves before atomics

    // ---- epilogue: per-token softmax + top-2 across the 64 lanes ----
    float local_psum = 0.f;
#pragma unroll
    for (int t = 0; t < 8; ++t) {
        float v = acc[t];
        float m = v;
#pragma unroll
        for (int off = 32; off; off >>= 1) m = fmaxf(m, __shfl_xor(m, off));
        float ex = __expf(v - m);
        float S = ex;
#pragma unroll
        for (int off = 32; off; off >>= 1) S += __shfl_xor(S, off);
        local_psum += ex / S;

        float bv = v; int bi = lane;
#pragma unroll
        for (int off = 32; off; off >>= 1) {
            float ov = __shfl_xor(bv, off);
            int   oi = __shfl_xor(bi, off);
            if (ov > bv || (ov == bv && oi < bi)) { bv = ov; bi = oi; }
        }
        float v1 = bv; int i1 = bi;
        float bv2 = (lane == i1) ? -3.4e38f : v; int bi2 = lane;
#pragma unroll
        for (int off = 32; off; off >>= 1) {
            float ov = __shfl_xor(bv2, off);
            int   oi = __shfl_xor(bi2, off);
            if (ov > bv2 || (ov == bv2 && oi < bi2)) { bv2 = ov; bi2 = oi; }
        }
        float v2 = bv2; int i2 = bi2;

        if (lane == 0) {
            float e1 = __expf(v1 - m);
            float e2 = __expf(v2 - m);
            float inv = 1.f / (e1 + e2);
            int tok = tko + t;
            out[tok * 2 + 0] = e1 * inv;
            out[tok * 2 + 1] = e2 * inv;
            out[OFF_IDX + tok * 2 + 0] = (float)i1;
            out[OFF_IDX + tok * 2 + 1] = (float)i2;
            atomicAdd(&hist_s[i1], 1);
            atomicAdd(&hist_s[i2], 1);
        }
    }

    psum_s[wave][lane] = local_psum;
    __syncthreads();
    if (wave == 0) {
        float s = psum_s[0][lane] + psum_s[1][lane] + psum_s[2][lane] + psum_s[3][lane];
        atomicAdd(&probsum_g[lane], s);
        atomicAdd(&hist_g[lane], (float)hist_s[lane]);
    }
}

__global__ void finalize_kernel(const float* __restrict__ probsum_g,
                                const float* __restrict__ hist_g,
                                float* __restrict__ out)
{
    int e = threadIdx.x;  // 64 threads
    float tpe = hist_g[e];
    out[OFF_HIST + e] = tpe;
    const float invT = 1.f / (float)TOKENS;
    float term = (tpe * invT) * (probsum_g[e] * invT);
#pragma unroll
    for (int off = 32; off; off >>= 1) term += __shfl_xor(term, off);
    if (e == 0) out[OFF_AUX] = term * (float)NEXP;
}

extern "C" void kernel_launch(void* const* d_in, const int* in_sizes, int n_in,
                              void* d_out, int out_size, void* d_ws, size_t ws_size,
                              hipStream_t stream) {
    const float* x  = (const float*)d_in[0];
    const float* gw = (const float*)d_in[1];
    float* out = (float*)d_out;
    float* ws  = (float*)d_ws;

    const bool use_w4 = ws_size >= (size_t)(W4_FLOATS + 128) * sizeof(float);
    dim3 grid(TOKENS / TPB);     // 512 blocks x 256 threads (4 waves)

    if (use_w4) {
        float* w4  = ws;                       // 512 KB transposed W
        float* acc = ws + W4_FLOATS;           // probsum[64] | hist[64]
        (void)hipMemsetAsync(acc, 0, 128 * sizeof(float), stream);
        transpose_w<<<dim3(128), 256, 0, stream>>>(gw, w4);
        router_kernel<true><<<grid, 256, 0, stream>>>(x, gw, w4, out, acc, acc + NEXP);
        finalize_kernel<<<1, 64, 0, stream>>>(acc, acc + NEXP, out);
    } else {
        float* acc = ws;
        (void)hipMemsetAsync(acc, 0, 128 * sizeof(float), stream);
        router_kernel<false><<<grid, 256, 0, stream>>>(x, gw, nullptr, out, acc, acc + NEXP);
        finalize_kernel<<<1, 64, 0, stream>>>(acc, acc + NEXP, out);
    }
}